// Round 11
// baseline (280.195 us; speedup 1.0000x reference)
//
#include <hip/hip_runtime.h>
#include <hip/hip_bf16.h>

#define N_NODES 100000
#define N_EDGES 1600000
#define N_LBL   1000000
#define XC 972
#define XO 588
#define D1 128
#define D2 64
#define PLACE_BLOCKS 512                     // grid-stride place blocks, launched first
#define GEMM1_BLOCKS ((N_NODES + 63) / 64)   // 1563
#define MEGA_BLOCKS  (PLACE_BLOCKS + GEMM1_BLOCKS)
// fixed CSR slot of 64 per node; Poisson(16) in-degree => P(deg>64) ~ 1e-20

typedef float f32x4 __attribute__((ext_vector_type(4)));
typedef float f32x2 __attribute__((ext_vector_type(2)));
typedef short bf16x8 __attribute__((ext_vector_type(8)));

__device__ inline unsigned f2bf(float f) {              // RNE f32 -> bf16 bits (cold paths)
    unsigned u = __float_as_uint(f);
    return (u + 0x7fffu + ((u >> 16) & 1u)) >> 16;
}
__device__ inline float bf_lo(unsigned v) { return __uint_as_float(v << 16); }
__device__ inline float bf_hi(unsigned v) { return __uint_as_float(v & 0xffff0000u); }
__device__ inline f32x2 bf2(unsigned v) {
    f32x2 r; r.x = bf_lo(v); r.y = bf_hi(v); return r;
}

__device__ inline unsigned pack_bf2(float lo, float hi) {
    union { __hip_bfloat162 h; unsigned u; } p;
    p.h = __float22bfloat162_rn(make_float2(lo, hi));   // v_cvt_pk_bf16_f32
    return p.u;
}
__device__ inline bf16x8 to_bf8(float4 a, float4 b) {
    union { __hip_bfloat162 h[4]; bf16x8 v; } u;
    u.h[0] = __float22bfloat162_rn(make_float2(a.x, a.y));
    u.h[1] = __float22bfloat162_rn(make_float2(a.z, a.w));
    u.h[2] = __float22bfloat162_rn(make_float2(b.x, b.y));
    u.h[3] = __float22bfloat162_rn(make_float2(b.z, b.w));
    return u.v;
}
// packed accumulate: a[0..3] += u (8 bf16) * s   -> v_pk_fma_f32 via contraction
__device__ inline void fma8p(f32x2 (&a)[4], uint4 u, f32x2 s) {
    a[0] += bf2(u.x) * s;
    a[1] += bf2(u.y) * s;
    a[2] += bf2(u.z) * s;
    a[3] += bf2(u.w) * s;
}
__device__ inline void add8p(f32x2 (&a)[4], uint4 u) {
    a[0] += bf2(u.x);
    a[1] += bf2(u.y);
    a[2] += bf2(u.z);
    a[3] += bf2(u.w);
}
__device__ inline f32x2 dot8p(uint4 a, uint4 c) {
    f32x2 r = bf2(a.x) * bf2(c.x);
    r += bf2(a.y) * bf2(c.y);
    r += bf2(a.z) * bf2(c.z);
    r += bf2(a.w) * bf2(c.w);
    return r;
}

// ------------- prep: zero cursor + pack W1/W2 into MFMA B-fragment order -------------
__global__ __launch_bounds__(256) void k_prep(const float* __restrict__ W1,
                                              const float* __restrict__ W2,
                                              unsigned short* __restrict__ w1p,
                                              unsigned short* __restrict__ w2p,
                                              unsigned* __restrict__ cursor) {
    int i = blockIdx.x * 256 + threadIdx.x;   // grid 392*256 = 100352
    if (i < N_NODES) cursor[i] = 0u;
    if (i < 49152) {
        int j = i & 7, lane = (i >> 3) & 63, nt = (i >> 9) & 7, ks = i >> 12;
        int k = ks * 32 + ((lane >> 4) << 3) + j;
        int n = (nt << 4) + (lane & 15);
        w1p[i] = (unsigned short)f2bf(W1[k * D1 + n]);
    } else if (i < 57344) {
        int t = i - 49152;
        int j = t & 7, lane = (t >> 3) & 63, nt = (t >> 9) & 3, ks = t >> 11;
        int k = ks * 32 + ((lane >> 4) << 3) + j;
        int n = (nt << 4) + (lane & 15);
        w2p[t] = (unsigned short)f2bf(W2[k * D2 + n]);
    }
}

// -- MEGA: first PLACE_BLOCKS = grid-stride CSR place (starts first, overlaps);
//    remaining GEMM1_BLOCKS = gemm1 (s1 UNscaled). --------------------------------
__global__ __launch_bounds__(256) void k_mega(const float* __restrict__ x,
                                              const unsigned short* __restrict__ w1p,
                                              unsigned short* __restrict__ s1,
                                              const int* __restrict__ erow,
                                              const int* __restrict__ ecol,
                                              unsigned* __restrict__ cursor,
                                              int* __restrict__ srcidx) {
    if (blockIdx.x < PLACE_BLOCKS) {
        // ---- place: grid-stride over edges; srcidx[c*64 + j] = row; cursor -> deg ----
        for (int e = blockIdx.x * 256 + threadIdx.x; e < N_EDGES;
             e += PLACE_BLOCKS * 256) {
            int c = ecol[e];
            unsigned j = atomicAdd(&cursor[c], 1u);
            srcidx[((size_t)c << 6) + j] = erow[e];
        }
    } else {
        // ---- GEMM1: s1 = bf16( x[:,588:] @ W1 )  (4 waves x 16 rows) ----
        const int g    = blockIdx.x - PLACE_BLOCKS;
        const int lane = threadIdx.x & 63;
        const int wid  = threadIdx.x >> 6;
        const int lrow = lane & 15;
        const int kq   = lane >> 4;

        const int row0 = g * 64 + wid * 16;
        const int rc = min(row0 + lrow, N_NODES - 1);
        const float* pA = x + (size_t)rc * XC + XO + (kq << 3);

        f32x4 acc[8];
#pragma unroll
        for (int t = 0; t < 8; ++t) acc[t] = (f32x4)0.f;

#pragma unroll 2
        for (int ks = 0; ks < 12; ++ks) {
            float4 a0 = *reinterpret_cast<const float4*>(pA + ks * 32);
            float4 a1 = *reinterpret_cast<const float4*>(pA + ks * 32 + 4);
            bf16x8 aA = to_bf8(a0, a1);
#pragma unroll
            for (int t = 0; t < 8; ++t) {
                bf16x8 bf = *reinterpret_cast<const bf16x8*>(
                    w1p + ((size_t)((ks * 8 + t) * 64 + lane) << 3));
                acc[t] = __builtin_amdgcn_mfma_f32_16x16x32_bf16(aA, bf, acc[t], 0, 0, 0);
            }
        }

        const int rowq = row0 + kq * 4;
#pragma unroll
        for (int r = 0; r < 4; ++r) {
            int rw = rowq + r;
            if (rw < N_NODES) {
#pragma unroll
                for (int t = 0; t < 8; ++t)
                    s1[(size_t)rw * D1 + lrow + t * 16] =
                        (unsigned short)f2bf(acc[t][r]);
            }
        }
    }
}

// ------- FUSED: gather1 (dinv[r]-weighted, MFMA-A layout) + relu/bias + GEMM2 --------
// wave = 16 nodes; lane: n = lane&15 (node/row), kq = lane>>4 (k-chunk).
// x4 unroll, 16 row-loads in flight; packed f32x2 accumulation.
__global__ __launch_bounds__(256) void k_fused(const unsigned short* __restrict__ s1,
                                               const int* __restrict__ srcidx,
                                               const unsigned* __restrict__ deg,
                                               const float* __restrict__ b1,
                                               const unsigned short* __restrict__ w2p,
                                               unsigned short* __restrict__ s2) {
    const int lane = threadIdx.x & 63;
    const int wid  = threadIdx.x >> 6;
    const int n    = lane & 15;
    const int kq   = lane >> 4;
    const int base = blockIdx.x * 64 + wid * 16;
    const int c  = base + n;
    const int cc = min(c, N_NODES - 1);

    const int cnt = (int)deg[cc];
    const float dc = rsqrtf((float)(cnt + 1));
    const f32x2 dc2 = {dc, dc};

    f32x2 acc[4][4];
#pragma unroll
    for (int p = 0; p < 4; ++p)
#pragma unroll
        for (int j = 0; j < 4; ++j) acc[p][j] = (f32x2)0.f;

    // self loop: dinv_c * s1'[cc]
    {
        const unsigned short* srow = s1 + (size_t)cc * D1 + (kq << 3);
        fma8p(acc[0], *reinterpret_cast<const uint4*>(srow),      dc2);
        fma8p(acc[1], *reinterpret_cast<const uint4*>(srow + 32), dc2);
        fma8p(acc[2], *reinterpret_cast<const uint4*>(srow + 64), dc2);
        fma8p(acc[3], *reinterpret_cast<const uint4*>(srow + 96), dc2);
    }

    const int* sp = srcidx + ((size_t)cc << 6);
    int j = 0;
    for (; j + 4 <= cnt; j += 4) {
        int4 idx = *reinterpret_cast<const int4*>(sp + j);
        const unsigned short* p0 = s1 + (size_t)idx.x * D1 + (kq << 3);
        const unsigned short* p1 = s1 + (size_t)idx.y * D1 + (kq << 3);
        const unsigned short* p2 = s1 + (size_t)idx.z * D1 + (kq << 3);
        const unsigned short* p3 = s1 + (size_t)idx.w * D1 + (kq << 3);
        unsigned g0 = deg[idx.x], g1 = deg[idx.y], g2 = deg[idx.z], g3 = deg[idx.w];
        uint4 a0 = *reinterpret_cast<const uint4*>(p0);
        uint4 a1 = *reinterpret_cast<const uint4*>(p0 + 32);
        uint4 a2 = *reinterpret_cast<const uint4*>(p0 + 64);
        uint4 a3 = *reinterpret_cast<const uint4*>(p0 + 96);
        uint4 b0 = *reinterpret_cast<const uint4*>(p1);
        uint4 b1x = *reinterpret_cast<const uint4*>(p1 + 32);
        uint4 b2 = *reinterpret_cast<const uint4*>(p1 + 64);
        uint4 b3 = *reinterpret_cast<const uint4*>(p1 + 96);
        uint4 c0 = *reinterpret_cast<const uint4*>(p2);
        uint4 c1 = *reinterpret_cast<const uint4*>(p2 + 32);
        uint4 c2 = *reinterpret_cast<const uint4*>(p2 + 64);
        uint4 c3 = *reinterpret_cast<const uint4*>(p2 + 96);
        uint4 e0 = *reinterpret_cast<const uint4*>(p3);
        uint4 e1 = *reinterpret_cast<const uint4*>(p3 + 32);
        uint4 e2 = *reinterpret_cast<const uint4*>(p3 + 64);
        uint4 e3 = *reinterpret_cast<const uint4*>(p3 + 96);
        f32x2 d0 = {0.f, 0.f}, d1 = d0, d2 = d0, d3 = d0;
        d0.x = d0.y = rsqrtf((float)(g0 + 1u));
        d1.x = d1.y = rsqrtf((float)(g1 + 1u));
        d2.x = d2.y = rsqrtf((float)(g2 + 1u));
        d3.x = d3.y = rsqrtf((float)(g3 + 1u));
        fma8p(acc[0], a0, d0); fma8p(acc[1], a1, d0);
        fma8p(acc[2], a2, d0); fma8p(acc[3], a3, d0);
        fma8p(acc[0], b0, d1); fma8p(acc[1], b1x, d1);
        fma8p(acc[2], b2, d1); fma8p(acc[3], b3, d1);
        fma8p(acc[0], c0, d2); fma8p(acc[1], c1, d2);
        fma8p(acc[2], c2, d2); fma8p(acc[3], c3, d2);
        fma8p(acc[0], e0, d3); fma8p(acc[1], e1, d3);
        fma8p(acc[2], e2, d3); fma8p(acc[3], e3, d3);
    }
    for (; j < cnt; ++j) {
        int r = sp[j];
        float drs = rsqrtf((float)(deg[r] + 1u));
        f32x2 dr = {drs, drs};
        const unsigned short* rr = s1 + (size_t)r * D1 + (kq << 3);
        fma8p(acc[0], *reinterpret_cast<const uint4*>(rr),      dr);
        fma8p(acc[1], *reinterpret_cast<const uint4*>(rr + 32), dr);
        fma8p(acc[2], *reinterpret_cast<const uint4*>(rr + 64), dr);
        fma8p(acc[3], *reinterpret_cast<const uint4*>(rr + 96), dr);
    }

    // ---- finish layer 1: h = relu(dinv_c * acc + b1), convert to A-fragments ----
    bf16x8 af[4];
#pragma unroll
    for (int p = 0; p < 4; ++p) {
        const float* bp = b1 + p * 32 + (kq << 3);
        float4 ba = *reinterpret_cast<const float4*>(bp);
        float4 bb = *reinterpret_cast<const float4*>(bp + 4);
        float4 h0 = make_float4(fmaxf(fmaf(acc[p][0].x, dc, ba.x), 0.f),
                                fmaxf(fmaf(acc[p][0].y, dc, ba.y), 0.f),
                                fmaxf(fmaf(acc[p][1].x, dc, ba.z), 0.f),
                                fmaxf(fmaf(acc[p][1].y, dc, ba.w), 0.f));
        float4 h1 = make_float4(fmaxf(fmaf(acc[p][2].x, dc, bb.x), 0.f),
                                fmaxf(fmaf(acc[p][2].y, dc, bb.y), 0.f),
                                fmaxf(fmaf(acc[p][3].x, dc, bb.z), 0.f),
                                fmaxf(fmaf(acc[p][3].y, dc, bb.w), 0.f));
        af[p] = to_bf8(h0, h1);
    }

    // ---- GEMM2: 16 nodes x 64 cols via 16 MFMAs ----
    f32x4 acc2[4];
#pragma unroll
    for (int nt = 0; nt < 4; ++nt) acc2[nt] = (f32x4)0.f;
#pragma unroll
    for (int ks = 0; ks < 4; ++ks)
#pragma unroll
        for (int nt = 0; nt < 4; ++nt) {
            bf16x8 bf = *reinterpret_cast<const bf16x8*>(
                w2p + ((size_t)((ks * 4 + nt) * 64 + lane) << 3));
            acc2[nt] = __builtin_amdgcn_mfma_f32_16x16x32_bf16(af[ks], bf, acc2[nt], 0, 0, 0);
        }

    // ---- epilogue: s2[row] = bf16(acc2 * dinv_row); C/D rows = kq*4+r, col = n ----
#pragma unroll
    for (int r = 0; r < 4; ++r) {
        int rw = base + kq * 4 + r;
        if (rw < N_NODES) {
            float dm = rsqrtf((float)(deg[rw] + 1u));
#pragma unroll
            for (int nt = 0; nt < 4; ++nt)
                s2[(size_t)rw * D2 + nt * 16 + n] =
                    (unsigned short)f2bf(acc2[nt][r] * dm);
        }
    }
}

// ---------------- gather2: z = bf16(dinv[c]*(s2[c]+sum s2[src]) + b2) ----------------
// 8 lanes per node, uint4 (8 bf16) per lane; unrolled x4; packed accumulation
__global__ __launch_bounds__(256) void k_gather2(const unsigned short* __restrict__ s2,
                                                 const int* __restrict__ srcidx,
                                                 const unsigned* __restrict__ deg,
                                                 const float* __restrict__ b,
                                                 uint4* __restrict__ zv) {
    const int c    = blockIdx.x * 32 + (threadIdx.x >> 3);
    const int l8   = threadIdx.x & 7;

    f32x2 a[4];
#pragma unroll
    for (int j = 0; j < 4; ++j) a[j] = (f32x2)0.f;
    add8p(a, *reinterpret_cast<const uint4*>(s2 + (size_t)c * D2 + (l8 << 3)));

    const int cnt = (int)deg[c];
    const int* sp = srcidx + ((size_t)c << 6);
    int j = 0;
    for (; j + 4 <= cnt; j += 4) {
        int4 idx = *reinterpret_cast<const int4*>(sp + j);
        uint4 u0 = *reinterpret_cast<const uint4*>(s2 + (size_t)idx.x * D2 + (l8 << 3));
        uint4 u1 = *reinterpret_cast<const uint4*>(s2 + (size_t)idx.y * D2 + (l8 << 3));
        uint4 u2 = *reinterpret_cast<const uint4*>(s2 + (size_t)idx.z * D2 + (l8 << 3));
        uint4 u3 = *reinterpret_cast<const uint4*>(s2 + (size_t)idx.w * D2 + (l8 << 3));
        add8p(a, u0); add8p(a, u1); add8p(a, u2); add8p(a, u3);
    }
    for (; j < cnt; ++j) {
        int r = sp[j];
        add8p(a, *reinterpret_cast<const uint4*>(s2 + (size_t)r * D2 + (l8 << 3)));
    }
    const float d = rsqrtf((float)(cnt + 1));
    const float4 b0 = reinterpret_cast<const float4*>(b)[l8 * 2];
    const float4 b1v = reinterpret_cast<const float4*>(b)[l8 * 2 + 1];
    uint4 o;
    o.x = pack_bf2(fmaf(a[0].x, d, b0.x),  fmaf(a[0].y, d, b0.y));
    o.y = pack_bf2(fmaf(a[1].x, d, b0.z),  fmaf(a[1].y, d, b0.w));
    o.z = pack_bf2(fmaf(a[2].x, d, b1v.x), fmaf(a[2].y, d, b1v.y));
    o.w = pack_bf2(fmaf(a[3].x, d, b1v.z), fmaf(a[3].y, d, b1v.w));
    zv[(size_t)c * 8 + l8] = o;
}

// ------- scoring: 2 edges per 8-lane group, all 4 z-row loads in flight --------------
__global__ __launch_bounds__(256) void k_score(const uint4* __restrict__ Z,
                                               const int* __restrict__ ea,
                                               const int* __restrict__ eb,
                                               float* __restrict__ out) {
    int tid = blockIdx.x * 256 + threadIdx.x;   // N_LBL*8/2 threads
    int p = tid >> 3;                           // edge pair [0, N_LBL/2)
    int l = tid & 7;
    int2 us = *reinterpret_cast<const int2*>(ea + 2 * p);
    int2 vs = *reinterpret_cast<const int2*>(eb + 2 * p);
    uint4 a0 = Z[(size_t)us.x * 8 + l];
    uint4 c0 = Z[(size_t)vs.x * 8 + l];
    uint4 a1 = Z[(size_t)us.y * 8 + l];
    uint4 c1 = Z[(size_t)vs.y * 8 + l];
    f32x2 q0 = dot8p(a0, c0);
    f32x2 q1 = dot8p(a1, c1);
    float p0 = q0.x + q0.y;
    float p1 = q1.x + q1.y;
    p0 += __shfl_down(p0, 4, 8);  p1 += __shfl_down(p1, 4, 8);
    p0 += __shfl_down(p0, 2, 8);  p1 += __shfl_down(p1, 2, 8);
    p0 += __shfl_down(p0, 1, 8);  p1 += __shfl_down(p1, 1, 8);
    if (l == 0) *reinterpret_cast<float2*>(out + 2 * p) = make_float2(p0, p1);
}

extern "C" void kernel_launch(void* const* d_in, const int* in_sizes, int n_in,
                              void* d_out, int out_size, void* d_ws, size_t ws_size,
                              hipStream_t stream) {
    const float* x   = (const float*)d_in[0];
    const int*   ei  = (const int*)d_in[1];   // [2, N_EDGES]: rows then cols
    const int*   eli = (const int*)d_in[2];   // [2, N_LBL]
    const float* W1  = (const float*)d_in[3];
    const float* b1  = (const float*)d_in[4];
    const float* W2  = (const float*)d_in[5];
    const float* b2  = (const float*)d_in[6];
    float* out = (float*)d_out;

    // workspace layout (byte offsets, 16B-aligned)
    char* ws = (char*)d_ws;
    unsigned*       cursor = (unsigned*)(ws + 0);               //   400,000 B (ends as deg)
    unsigned short* w1p    = (unsigned short*)(ws + 400000);    //    98,304 B
    unsigned short* w2p    = (unsigned short*)(ws + 498304);    //    16,384 B
    int*            srcidx = (int*)(ws + 514688);               // 25,600,000 B
    unsigned short* s1     = (unsigned short*)(ws + 26114688);  // 25.6 MB
    unsigned short* s2     = (unsigned short*)(ws + 51714688);  // 12.8 MB
    unsigned short* z      = (unsigned short*)(ws + 64514688);  // 12.8 MB

    k_prep   <<<392, 256, 0, stream>>>(W1, W2, w1p, w2p, cursor);
    k_mega   <<<MEGA_BLOCKS, 256, 0, stream>>>(x, w1p, s1, ei, ei + N_EDGES,
                                               cursor, srcidx);
    k_fused  <<<(N_NODES + 63) / 64, 256, 0, stream>>>(s1, srcidx, cursor, b1, w2p, s2);
    k_gather2<<<N_NODES / 32, 256, 0, stream>>>(s2, srcidx, cursor, b2, (uint4*)z);
    k_score  <<<(size_t)N_LBL * 8 / 2 / 256, 256, 0, stream>>>((const uint4*)z, eli,
                                                               eli + N_LBL, out);
}

// Round 12
// 270.373 us; speedup vs baseline: 1.0363x; 1.0363x over previous
//
#include <hip/hip_runtime.h>
#include <hip/hip_bf16.h>

#define N_NODES 100000
#define N_EDGES 1600000
#define N_LBL   1000000
#define XC 972
#define XO 588
#define D1 128
#define D2 64
#define GEMM1_BLOCKS ((N_NODES + 63) / 64)   // 1563
#define PLACE_BLOCKS (N_EDGES / 256)         // 6250
// fixed CSR slot of 64 per node; Poisson(16) in-degree => P(deg>64) ~ 1e-20

typedef float f32x4 __attribute__((ext_vector_type(4)));
typedef short bf16x8 __attribute__((ext_vector_type(8)));

__device__ inline unsigned f2bf(float f) {              // RNE f32 -> bf16 bits (cold paths)
    unsigned u = __float_as_uint(f);
    return (u + 0x7fffu + ((u >> 16) & 1u)) >> 16;
}
__device__ inline float bf_lo(unsigned v) { return __uint_as_float(v << 16); }
__device__ inline float bf_hi(unsigned v) { return __uint_as_float(v & 0xffff0000u); }

__device__ inline unsigned pack_bf2(float lo, float hi) {
    union { __hip_bfloat162 h; unsigned u; } p;
    p.h = __float22bfloat162_rn(make_float2(lo, hi));   // v_cvt_pk_bf16_f32
    return p.u;
}
__device__ inline bf16x8 to_bf8(float4 a, float4 b) {
    union { __hip_bfloat162 h[4]; bf16x8 v; } u;
    u.h[0] = __float22bfloat162_rn(make_float2(a.x, a.y));
    u.h[1] = __float22bfloat162_rn(make_float2(a.z, a.w));
    u.h[2] = __float22bfloat162_rn(make_float2(b.x, b.y));
    u.h[3] = __float22bfloat162_rn(make_float2(b.z, b.w));
    return u.v;
}
__device__ inline void add8(float (&a)[8], uint4 u) {
    a[0] += bf_lo(u.x); a[1] += bf_hi(u.x);
    a[2] += bf_lo(u.y); a[3] += bf_hi(u.y);
    a[4] += bf_lo(u.z); a[5] += bf_hi(u.z);
    a[6] += bf_lo(u.w); a[7] += bf_hi(u.w);
}
__device__ inline void fma8(float (&a)[8], uint4 u, float s) {
    a[0] = fmaf(bf_lo(u.x), s, a[0]); a[1] = fmaf(bf_hi(u.x), s, a[1]);
    a[2] = fmaf(bf_lo(u.y), s, a[2]); a[3] = fmaf(bf_hi(u.y), s, a[3]);
    a[4] = fmaf(bf_lo(u.z), s, a[4]); a[5] = fmaf(bf_hi(u.z), s, a[5]);
    a[6] = fmaf(bf_lo(u.w), s, a[6]); a[7] = fmaf(bf_hi(u.w), s, a[7]);
}
__device__ inline float dot8(uint4 a, uint4 c) {
    return bf_lo(a.x) * bf_lo(c.x) + bf_hi(a.x) * bf_hi(c.x)
         + bf_lo(a.y) * bf_lo(c.y) + bf_hi(a.y) * bf_hi(c.y)
         + bf_lo(a.z) * bf_lo(c.z) + bf_hi(a.z) * bf_hi(c.z)
         + bf_lo(a.w) * bf_lo(c.w) + bf_hi(a.w) * bf_hi(c.w);
}

// ------------- prep: zero cursor + pack W1/W2 into MFMA B-fragment order -------------
__global__ __launch_bounds__(256) void k_prep(const float* __restrict__ W1,
                                              const float* __restrict__ W2,
                                              unsigned short* __restrict__ w1p,
                                              unsigned short* __restrict__ w2p,
                                              unsigned* __restrict__ cursor) {
    int i = blockIdx.x * 256 + threadIdx.x;   // grid 392*256 = 100352
    if (i < N_NODES) cursor[i] = 0u;
    if (i < 49152) {
        int j = i & 7, lane = (i >> 3) & 63, nt = (i >> 9) & 7, ks = i >> 12;
        int k = ks * 32 + ((lane >> 4) << 3) + j;
        int n = (nt << 4) + (lane & 15);
        w1p[i] = (unsigned short)f2bf(W1[k * D1 + n]);
    } else if (i < 57344) {
        int t = i - 49152;
        int j = t & 7, lane = (t >> 3) & 63, nt = (t >> 9) & 3, ks = t >> 11;
        int k = ks * 32 + ((lane >> 4) << 3) + j;
        int n = (nt << 4) + (lane & 15);
        w2p[t] = (unsigned short)f2bf(W2[k * D2 + n]);
    }
}

// ------------- MEGA: [0,GEMM1_BLOCKS) gemm1 (s1 UNscaled) | rest: CSR place ----------
__global__ __launch_bounds__(256) void k_mega(const float* __restrict__ x,
                                              const unsigned short* __restrict__ w1p,
                                              unsigned short* __restrict__ s1,
                                              const int* __restrict__ erow,
                                              const int* __restrict__ ecol,
                                              unsigned* __restrict__ cursor,
                                              int* __restrict__ srcidx) {
    if (blockIdx.x < GEMM1_BLOCKS) {
        // ---- GEMM1: s1 = bf16( x[:,588:] @ W1 )  (4 waves x 16 rows) ----
        const int lane = threadIdx.x & 63;
        const int wid  = threadIdx.x >> 6;
        const int lrow = lane & 15;
        const int kq   = lane >> 4;

        const int row0 = blockIdx.x * 64 + wid * 16;
        const int rc = min(row0 + lrow, N_NODES - 1);
        const float* pA = x + (size_t)rc * XC + XO + (kq << 3);

        f32x4 acc[8];
#pragma unroll
        for (int t = 0; t < 8; ++t) acc[t] = (f32x4)0.f;

#pragma unroll 2
        for (int ks = 0; ks < 12; ++ks) {
            float4 a0 = *reinterpret_cast<const float4*>(pA + ks * 32);
            float4 a1 = *reinterpret_cast<const float4*>(pA + ks * 32 + 4);
            bf16x8 aA = to_bf8(a0, a1);
#pragma unroll
            for (int t = 0; t < 8; ++t) {
                bf16x8 bf = *reinterpret_cast<const bf16x8*>(
                    w1p + ((size_t)((ks * 8 + t) * 64 + lane) << 3));
                acc[t] = __builtin_amdgcn_mfma_f32_16x16x32_bf16(aA, bf, acc[t], 0, 0, 0);
            }
        }

        const int rowq = row0 + kq * 4;
#pragma unroll
        for (int r = 0; r < 4; ++r) {
            int rw = rowq + r;
            if (rw < N_NODES) {
#pragma unroll
                for (int t = 0; t < 8; ++t)
                    s1[(size_t)rw * D1 + lrow + t * 16] =
                        (unsigned short)f2bf(acc[t][r]);
            }
        }
    } else {
        // ---- place: srcidx[c*64 + j] = row; cursor ends as deg ----
        int e = (blockIdx.x - GEMM1_BLOCKS) * 256 + threadIdx.x;
        int c = ecol[e];
        unsigned j = atomicAdd(&cursor[c], 1u);
        srcidx[((size_t)c << 6) + j] = erow[e];
    }
}

// ------- FUSED: gather1 (dinv[r]-weighted, MFMA-A layout) + relu/bias + GEMM2 --------
// wave = 16 nodes; lane: n = lane&15 (node/row), kq = lane>>4 (k-chunk).
// x4 unroll, 16 row-loads in flight, next-iter index prefetched.
__global__ __launch_bounds__(256) void k_fused(const unsigned short* __restrict__ s1,
                                               const int* __restrict__ srcidx,
                                               const unsigned* __restrict__ deg,
                                               const float* __restrict__ b1,
                                               const unsigned short* __restrict__ w2p,
                                               unsigned short* __restrict__ s2) {
    const int lane = threadIdx.x & 63;
    const int wid  = threadIdx.x >> 6;
    const int n    = lane & 15;
    const int kq   = lane >> 4;
    const int base = blockIdx.x * 64 + wid * 16;
    const int c  = base + n;
    const int cc = min(c, N_NODES - 1);

    const int cnt = (int)deg[cc];
    const float dc = rsqrtf((float)(cnt + 1));

    float acc[4][8];
#pragma unroll
    for (int p = 0; p < 4; ++p)
#pragma unroll
        for (int j = 0; j < 8; ++j) acc[p][j] = 0.f;

    // self loop: dinv_c * s1'[cc]
    {
        const unsigned short* srow = s1 + (size_t)cc * D1 + (kq << 3);
        fma8(acc[0], *reinterpret_cast<const uint4*>(srow),      dc);
        fma8(acc[1], *reinterpret_cast<const uint4*>(srow + 32), dc);
        fma8(acc[2], *reinterpret_cast<const uint4*>(srow + 64), dc);
        fma8(acc[3], *reinterpret_cast<const uint4*>(srow + 96), dc);
    }

    const int* sp = srcidx + ((size_t)cc << 6);
    int j = 0;
    int4 idx;
    if (cnt >= 4) idx = *reinterpret_cast<const int4*>(sp);
    for (; j + 4 <= cnt; j += 4) {
        int4 cur = idx;
        if (j + 8 <= cnt) idx = *reinterpret_cast<const int4*>(sp + j + 4);
        const unsigned short* p0 = s1 + (size_t)cur.x * D1 + (kq << 3);
        const unsigned short* p1 = s1 + (size_t)cur.y * D1 + (kq << 3);
        const unsigned short* p2 = s1 + (size_t)cur.z * D1 + (kq << 3);
        const unsigned short* p3 = s1 + (size_t)cur.w * D1 + (kq << 3);
        unsigned g0 = deg[cur.x], g1 = deg[cur.y], g2 = deg[cur.z], g3 = deg[cur.w];
        uint4 a0 = *reinterpret_cast<const uint4*>(p0);
        uint4 a1 = *reinterpret_cast<const uint4*>(p0 + 32);
        uint4 a2 = *reinterpret_cast<const uint4*>(p0 + 64);
        uint4 a3 = *reinterpret_cast<const uint4*>(p0 + 96);
        uint4 b0 = *reinterpret_cast<const uint4*>(p1);
        uint4 b1x = *reinterpret_cast<const uint4*>(p1 + 32);
        uint4 b2 = *reinterpret_cast<const uint4*>(p1 + 64);
        uint4 b3 = *reinterpret_cast<const uint4*>(p1 + 96);
        uint4 c0 = *reinterpret_cast<const uint4*>(p2);
        uint4 c1 = *reinterpret_cast<const uint4*>(p2 + 32);
        uint4 c2 = *reinterpret_cast<const uint4*>(p2 + 64);
        uint4 c3 = *reinterpret_cast<const uint4*>(p2 + 96);
        uint4 e0 = *reinterpret_cast<const uint4*>(p3);
        uint4 e1 = *reinterpret_cast<const uint4*>(p3 + 32);
        uint4 e2 = *reinterpret_cast<const uint4*>(p3 + 64);
        uint4 e3 = *reinterpret_cast<const uint4*>(p3 + 96);
        float d0 = rsqrtf((float)(g0 + 1u));
        float d1 = rsqrtf((float)(g1 + 1u));
        float d2 = rsqrtf((float)(g2 + 1u));
        float d3 = rsqrtf((float)(g3 + 1u));
        fma8(acc[0], a0, d0); fma8(acc[1], a1, d0);
        fma8(acc[2], a2, d0); fma8(acc[3], a3, d0);
        fma8(acc[0], b0, d1); fma8(acc[1], b1x, d1);
        fma8(acc[2], b2, d1); fma8(acc[3], b3, d1);
        fma8(acc[0], c0, d2); fma8(acc[1], c1, d2);
        fma8(acc[2], c2, d2); fma8(acc[3], c3, d2);
        fma8(acc[0], e0, d3); fma8(acc[1], e1, d3);
        fma8(acc[2], e2, d3); fma8(acc[3], e3, d3);
    }
    for (; j < cnt; ++j) {
        int r = sp[j];
        float dr = rsqrtf((float)(deg[r] + 1u));
        const unsigned short* rr = s1 + (size_t)r * D1 + (kq << 3);
        fma8(acc[0], *reinterpret_cast<const uint4*>(rr),      dr);
        fma8(acc[1], *reinterpret_cast<const uint4*>(rr + 32), dr);
        fma8(acc[2], *reinterpret_cast<const uint4*>(rr + 64), dr);
        fma8(acc[3], *reinterpret_cast<const uint4*>(rr + 96), dr);
    }

    // ---- finish layer 1: h = relu(dinv_c * acc + b1), convert to A-fragments ----
    bf16x8 af[4];
#pragma unroll
    for (int p = 0; p < 4; ++p) {
        const float* bp = b1 + p * 32 + (kq << 3);
        float4 ba = *reinterpret_cast<const float4*>(bp);
        float4 bb = *reinterpret_cast<const float4*>(bp + 4);
        float4 h0 = make_float4(fmaxf(fmaf(acc[p][0], dc, ba.x), 0.f),
                                fmaxf(fmaf(acc[p][1], dc, ba.y), 0.f),
                                fmaxf(fmaf(acc[p][2], dc, ba.z), 0.f),
                                fmaxf(fmaf(acc[p][3], dc, ba.w), 0.f));
        float4 h1 = make_float4(fmaxf(fmaf(acc[p][4], dc, bb.x), 0.f),
                                fmaxf(fmaf(acc[p][5], dc, bb.y), 0.f),
                                fmaxf(fmaf(acc[p][6], dc, bb.z), 0.f),
                                fmaxf(fmaf(acc[p][7], dc, bb.w), 0.f));
        af[p] = to_bf8(h0, h1);
    }

    // ---- GEMM2: 16 nodes x 64 cols via 16 MFMAs ----
    f32x4 acc2[4];
#pragma unroll
    for (int nt = 0; nt < 4; ++nt) acc2[nt] = (f32x4)0.f;
#pragma unroll
    for (int ks = 0; ks < 4; ++ks)
#pragma unroll
        for (int nt = 0; nt < 4; ++nt) {
            bf16x8 bf = *reinterpret_cast<const bf16x8*>(
                w2p + ((size_t)((ks * 4 + nt) * 64 + lane) << 3));
            acc2[nt] = __builtin_amdgcn_mfma_f32_16x16x32_bf16(af[ks], bf, acc2[nt], 0, 0, 0);
        }

    // ---- epilogue: s2[row] = bf16(acc2 * dinv_row); C/D rows = kq*4+r, col = n ----
#pragma unroll
    for (int r = 0; r < 4; ++r) {
        int rw = base + kq * 4 + r;
        if (rw < N_NODES) {
            float dm = rsqrtf((float)(deg[rw] + 1u));
#pragma unroll
            for (int nt = 0; nt < 4; ++nt)
                s2[(size_t)rw * D2 + nt * 16 + n] =
                    (unsigned short)f2bf(acc2[nt][r] * dm);
        }
    }
}

// ---------------- gather2: z = bf16(dinv[c]*(s2[c]+sum s2[src]) + b2) ----------------
// 8 lanes per node, uint4 (8 bf16) per lane; neighbor loop unrolled x8
__global__ __launch_bounds__(256) void k_gather2(const unsigned short* __restrict__ s2,
                                                 const int* __restrict__ srcidx,
                                                 const unsigned* __restrict__ deg,
                                                 const float* __restrict__ b,
                                                 uint4* __restrict__ zv) {
    const int c    = blockIdx.x * 32 + (threadIdx.x >> 3);
    const int l8   = threadIdx.x & 7;

    float a[8];
#pragma unroll
    for (int j = 0; j < 8; ++j) a[j] = 0.f;
    add8(a, *reinterpret_cast<const uint4*>(s2 + (size_t)c * D2 + (l8 << 3)));

    const int cnt = (int)deg[c];
    const int* sp = srcidx + ((size_t)c << 6);
    int j = 0;
    for (; j + 8 <= cnt; j += 8) {
        int4 i0 = *reinterpret_cast<const int4*>(sp + j);
        int4 i1 = *reinterpret_cast<const int4*>(sp + j + 4);
        uint4 u0 = *reinterpret_cast<const uint4*>(s2 + (size_t)i0.x * D2 + (l8 << 3));
        uint4 u1 = *reinterpret_cast<const uint4*>(s2 + (size_t)i0.y * D2 + (l8 << 3));
        uint4 u2 = *reinterpret_cast<const uint4*>(s2 + (size_t)i0.z * D2 + (l8 << 3));
        uint4 u3 = *reinterpret_cast<const uint4*>(s2 + (size_t)i0.w * D2 + (l8 << 3));
        uint4 u4 = *reinterpret_cast<const uint4*>(s2 + (size_t)i1.x * D2 + (l8 << 3));
        uint4 u5 = *reinterpret_cast<const uint4*>(s2 + (size_t)i1.y * D2 + (l8 << 3));
        uint4 u6 = *reinterpret_cast<const uint4*>(s2 + (size_t)i1.z * D2 + (l8 << 3));
        uint4 u7 = *reinterpret_cast<const uint4*>(s2 + (size_t)i1.w * D2 + (l8 << 3));
        add8(a, u0); add8(a, u1); add8(a, u2); add8(a, u3);
        add8(a, u4); add8(a, u5); add8(a, u6); add8(a, u7);
    }
    for (; j + 4 <= cnt; j += 4) {
        int4 idx = *reinterpret_cast<const int4*>(sp + j);
        uint4 u0 = *reinterpret_cast<const uint4*>(s2 + (size_t)idx.x * D2 + (l8 << 3));
        uint4 u1 = *reinterpret_cast<const uint4*>(s2 + (size_t)idx.y * D2 + (l8 << 3));
        uint4 u2 = *reinterpret_cast<const uint4*>(s2 + (size_t)idx.z * D2 + (l8 << 3));
        uint4 u3 = *reinterpret_cast<const uint4*>(s2 + (size_t)idx.w * D2 + (l8 << 3));
        add8(a, u0); add8(a, u1); add8(a, u2); add8(a, u3);
    }
    for (; j < cnt; ++j) {
        int r = sp[j];
        add8(a, *reinterpret_cast<const uint4*>(s2 + (size_t)r * D2 + (l8 << 3)));
    }
    const float d = rsqrtf((float)(cnt + 1));
    const float4 b0 = reinterpret_cast<const float4*>(b)[l8 * 2];
    const float4 b1v = reinterpret_cast<const float4*>(b)[l8 * 2 + 1];
    uint4 o;
    o.x = pack_bf2(fmaf(a[0], d, b0.x),  fmaf(a[1], d, b0.y));
    o.y = pack_bf2(fmaf(a[2], d, b0.z),  fmaf(a[3], d, b0.w));
    o.z = pack_bf2(fmaf(a[4], d, b1v.x), fmaf(a[5], d, b1v.y));
    o.w = pack_bf2(fmaf(a[6], d, b1v.z), fmaf(a[7], d, b1v.w));
    zv[(size_t)c * 8 + l8] = o;
}

// ------- scoring: 2 edges per 8-lane group, all 4 z-row loads in flight --------------
__global__ __launch_bounds__(256) void k_score(const uint4* __restrict__ Z,
                                               const int* __restrict__ ea,
                                               const int* __restrict__ eb,
                                               float* __restrict__ out) {
    int tid = blockIdx.x * 256 + threadIdx.x;   // N_LBL*8/2 threads
    int p = tid >> 3;                           // edge pair [0, N_LBL/2)
    int l = tid & 7;
    int2 us = *reinterpret_cast<const int2*>(ea + 2 * p);
    int2 vs = *reinterpret_cast<const int2*>(eb + 2 * p);
    uint4 a0 = Z[(size_t)us.x * 8 + l];
    uint4 c0 = Z[(size_t)vs.x * 8 + l];
    uint4 a1 = Z[(size_t)us.y * 8 + l];
    uint4 c1 = Z[(size_t)vs.y * 8 + l];
    float p0 = dot8(a0, c0);
    float p1 = dot8(a1, c1);
    p0 += __shfl_down(p0, 4, 8);  p1 += __shfl_down(p1, 4, 8);
    p0 += __shfl_down(p0, 2, 8);  p1 += __shfl_down(p1, 2, 8);
    p0 += __shfl_down(p0, 1, 8);  p1 += __shfl_down(p1, 1, 8);
    if (l == 0) *reinterpret_cast<float2*>(out + 2 * p) = make_float2(p0, p1);
}

extern "C" void kernel_launch(void* const* d_in, const int* in_sizes, int n_in,
                              void* d_out, int out_size, void* d_ws, size_t ws_size,
                              hipStream_t stream) {
    const float* x   = (const float*)d_in[0];
    const int*   ei  = (const int*)d_in[1];   // [2, N_EDGES]: rows then cols
    const int*   eli = (const int*)d_in[2];   // [2, N_LBL]
    const float* W1  = (const float*)d_in[3];
    const float* b1  = (const float*)d_in[4];
    const float* W2  = (const float*)d_in[5];
    const float* b2  = (const float*)d_in[6];
    float* out = (float*)d_out;

    // workspace layout (byte offsets, 16B-aligned)
    char* ws = (char*)d_ws;
    unsigned*       cursor = (unsigned*)(ws + 0);               //   400,000 B (ends as deg)
    unsigned short* w1p    = (unsigned short*)(ws + 400000);    //    98,304 B
    unsigned short* w2p    = (unsigned short*)(ws + 498304);    //    16,384 B
    int*            srcidx = (int*)(ws + 514688);               // 25,600,000 B
    unsigned short* s1     = (unsigned short*)(ws + 26114688);  // 25.6 MB
    unsigned short* s2     = (unsigned short*)(ws + 51714688);  // 12.8 MB
    unsigned short* z      = (unsigned short*)(ws + 64514688);  // 12.8 MB

    k_prep   <<<392, 256, 0, stream>>>(W1, W2, w1p, w2p, cursor);
    k_mega   <<<GEMM1_BLOCKS + PLACE_BLOCKS, 256, 0, stream>>>(x, w1p, s1, ei,
                                                               ei + N_EDGES, cursor, srcidx);
    k_fused  <<<(N_NODES + 63) / 64, 256, 0, stream>>>(s1, srcidx, cursor, b1, w2p, s2);
    k_gather2<<<N_NODES / 32, 256, 0, stream>>>(s2, srcidx, cursor, b2, (uint4*)z);
    k_score  <<<(size_t)N_LBL * 8 / 2 / 256, 256, 0, stream>>>((const uint4*)z, eli,
                                                               eli + N_LBL, out);
}